// Round 6
// baseline (101.833 us; speedup 1.0000x reference)
//
#include <hip/hip_runtime.h>

typedef float f4  __attribute__((ext_vector_type(4)));
typedef short s8v __attribute__((ext_vector_type(8)));
typedef short s4v __attribute__((ext_vector_type(4)));

#define BB    2
#define DDIM  1024
#define LSEQ  8192
#define LC    128
#define TD    16      // channels per block = 4 groups, 1 group per wave
#define TL    512     // l-extent per block
#define HALO  128
#define ZSTR  648     // bf16 row stride: 640 data + 8 pad
#define KSTR  176     // padded filter row: index = m + KOFF, m ∈ [-16, 160)
#define KOFF  16

// round-to-nearest-even fp32 -> bf16, packed pair (lo in bits 0-15)
__device__ __forceinline__ unsigned bf16pk(float lo, float hi) {
    unsigned a = __float_as_uint(lo), b = __float_as_uint(hi);
    a = (a + 0x7FFFu + ((a >> 16) & 1u)) >> 16;
    b = (b + 0x7FFFu + ((b >> 16) & 1u));
    return (a & 0xFFFFu) | (b & 0xFFFF0000u);
}
__device__ __forceinline__ float bf2f(short s) {
    return __uint_as_float(((unsigned)(unsigned short)s) << 16);
}

union U8 { s8v s; unsigned u[4]; };

__global__ __launch_bounds__(256, 5) void hyena_mfma_kernel(
    const float* __restrict__ x1,
    const float* __restrict__ x2,
    const float* __restrict__ v,
    const float* __restrict__ h,
    const float* __restrict__ cb,
    float* __restrict__ out)
{
    __shared__ union SM {
        struct { short zb[TD][ZSTR]; float kl[4][KSTR]; } s1;  // z (bf16) + filters
        f4 ob[TD][TL/4];                                        // fp32 out staging (32 KB)
    } sm;

    const int t  = threadIdx.x;
    const int d0 = blockIdx.x * TD;
    const int l0 = blockIdx.y * TL;
    const int b  = blockIdx.z;
    const int wv = t >> 6, lane = t & 63;

    // ---- phase 0: issue ALL z-staging loads into registers (long-latency first) ----
    const int r = t & 15, sbase = t >> 4;
    const size_t rb = ((size_t)(b*DDIM + d0 + r)) * LSEQ;
    f4 xa0[5], xa1[5], xw0[5], xw1[5];
    #pragma unroll
    for (int it = 0; it < 5; ++it) {
        const int gl = l0 - HALO + (sbase + 16*it)*8;
        if (gl >= 0) {
            xa0[it] = *(const f4*)(x2 + rb + gl);
            xa1[it] = *(const f4*)(x2 + rb + gl + 4);
            xw0[it] = *(const f4*)(v  + rb + gl);
            xw1[it] = *(const f4*)(v  + rb + gl + 4);
        }
    }

    // ---- wave-local filter build: wave w builds kl[w] for its own group ----
    // (no block barrier needed between this and the A-frag gather below)
    {
        const int g = (d0 >> 2) + wv;
        const float dd = __expf((float)g * (2.0f/255.0f) * 2.302585092994046f); // 10^(2g/255)
        for (int mi = lane; mi < KSTR; mi += 64) {
            const int m = mi - KOFF;
            float val = 0.f;
            if (m >= 0 && m < LC)
                val = h[g*LC + m] * __expf(-dd * (float)m * (1.0f/127.0f));
            sm.s1.kl[wv][mi] = val;
        }
    }

    // ---- lane geometry (MFMA 16x16x32) ----
    const int j  = lane & 15, kb = lane >> 4;
    const int qj = j & 3,  cc = j >> 2;
    const int row = wv*4 + cc;

    // ---- A-frags (pre-barrier; overlaps other waves' staging + own z latency):
    //      A_u[i,p] = k_pad[i - p + 16 + 32u], i = j, p = 8*kb + e ----
    s8v afr[5];
    #pragma unroll
    for (int u = 0; u < 5; ++u) {
        const int M0 = j - 8*kb + 16 + 32*u;
        float kv[8];
        #pragma unroll
        for (int e = 0; e < 8; ++e) kv[e] = sm.s1.kl[wv][M0 - e + KOFF];
        U8 aa;
        aa.u[0] = bf16pk(kv[0], kv[1]);
        aa.u[1] = bf16pk(kv[2], kv[3]);
        aa.u[2] = bf16pk(kv[4], kv[5]);
        aa.u[3] = bf16pk(kv[6], kv[7]);
        afr[u] = aa.s;
    }

    // ---- convert staged regs -> bf16 z in LDS ----
    #pragma unroll
    for (int it = 0; it < 5; ++it) {
        const int s = sbase + 16*it;
        const int gl = l0 - HALO + s*8;
        U8 zz; zz.s = (s8v){0,0,0,0,0,0,0,0};
        if (gl >= 0) {
            const f4 z0 = xa0[it]*xw0[it], z1 = xa1[it]*xw1[it];
            zz.u[0] = bf16pk(z0[0], z0[1]);
            zz.u[1] = bf16pk(z0[2], z0[3]);
            zz.u[2] = bf16pk(z1[0], z1[1]);
            zz.u[3] = bf16pk(z1[2], z1[3]);
        }
        *(s8v*)&sm.s1.zb[r][s*8] = zz.s;
    }

    // ---- x1 prefetch (consumed post-MFMA; latency hides under barrier+chains) ----
    const size_t chb = ((size_t)(b*DDIM + d0 + row)) * LSEQ + l0;
    f4 x1r[8];
    #pragma unroll
    for (int ci = 0; ci < 8; ++ci)
        x1r[ci] = *(const f4*)(x1 + chb + 64*ci + 16*qj + 4*kb);
    const float bd = cb[d0 + row];
    __syncthreads();

    // ---- 8 chains: 5 banded-Toeplitz MFMAs each; bias from LDS bf16 z; gate x1 ----
    f4 ov[8];
    #pragma unroll
    for (int ci = 0; ci < 8; ++ci) {
        const int L = 64*ci + 16*qj;
        f4 acc = {0.f, 0.f, 0.f, 0.f};
        #pragma unroll
        for (int u = 0; u < 5; ++u) {
            int bi = 112 + L + 8*kb - 32*u;      // zb idx of B_u[p=8kb..], incl. halo
            bi = bi < 0 ? 0 : bi;                // clamped reads pair with A == 0
            const s8v bf = *(const s8v*)&sm.s1.zb[row][bi];
            acc = __builtin_amdgcn_mfma_f32_16x16x32_bf16(afr[u], bf, acc, 0, 0, 0);
        }
        const int lo = L + 4*kb;                 // lane's 4 output l's: lo..lo+3
        const s4v z4 = *(const s4v*)&sm.s1.zb[row][HALO + lo];
        f4 o;
        o[0] = (acc[0] + bf2f(z4[0])*bd) * x1r[ci][0];
        o[1] = (acc[1] + bf2f(z4[1])*bd) * x1r[ci][1];
        o[2] = (acc[2] + bf2f(z4[2])*bd) * x1r[ci][2];
        o[3] = (acc[3] + bf2f(z4[3])*bd) * x1r[ci][3];
        ov[ci] = o;
    }
    __syncthreads();                             // z dead; reuse LDS as fp32 out staging

    // ---- stage D results (row-XOR swizzled f4) ----
    #pragma unroll
    for (int ci = 0; ci < 8; ++ci) {
        const int J = (4*ci + qj)*4 + kb;
        sm.ob[row][J ^ (row & 7)] = ov[ci];
    }
    __syncthreads();

    // ---- transposed write-out: full 64B lines at out[b, l0+l, d0..d0+15] ----
    const int seg = t & 3;
    #pragma unroll
    for (int it = 0; it < 8; ++it) {
        const int ll = (t >> 2) + it*64;
        const int J = ll >> 2, e = ll & 3;
        f4 o;
        #pragma unroll
        for (int rr = 0; rr < 4; ++rr) {
            const int r2 = seg*4 + rr;
            o[rr] = ((const float*)&sm.ob[r2][J ^ (r2 & 7)])[e];
        }
        *(f4*)(out + ((size_t)b*LSEQ + l0 + ll)*DDIM + d0 + seg*4) = o;
    }
}

extern "C" void kernel_launch(void* const* d_in, const int* in_sizes, int n_in,
                              void* d_out, int out_size, void* d_ws, size_t ws_size,
                              hipStream_t stream) {
    const float* x1 = (const float*)d_in[0];
    const float* x2 = (const float*)d_in[1];
    const float* v  = (const float*)d_in[2];
    const float* h  = (const float*)d_in[3];
    const float* cb = (const float*)d_in[4];
    float* outp = (float*)d_out;
    dim3 grid(DDIM/TD, LSEQ/TL, BB);
    hipLaunchKernelGGL(hyena_mfma_kernel, grid, dim3(256), 0, stream,
                       x1, x2, v, h, cb, outp);
}

// Round 7
// 90.384 us; speedup vs baseline: 1.1267x; 1.1267x over previous
//
#include <hip/hip_runtime.h>

typedef float f4  __attribute__((ext_vector_type(4)));
typedef short s8v __attribute__((ext_vector_type(8)));
typedef short s4v __attribute__((ext_vector_type(4)));

#define BB    2
#define DDIM  1024
#define LSEQ  8192
#define LC    128
#define TD    16      // channels per block = 4 groups, 1 group per wave
#define TL    512     // l-extent per block
#define HALO  128
#define ZSTR  648     // bf16 row stride: 640 data + 8 pad
#define KSTR  176     // padded filter row: index = m + KOFF, m ∈ [-16, 160)
#define KOFF  16
#define OB2   (TL/8)  // 64 f4 per row: half-tile output staging

// round-to-nearest-even fp32 -> bf16, packed pair (lo in bits 0-15)
__device__ __forceinline__ unsigned bf16pk(float lo, float hi) {
    unsigned a = __float_as_uint(lo), b = __float_as_uint(hi);
    a = (a + 0x7FFFu + ((a >> 16) & 1u)) >> 16;
    b = (b + 0x7FFFu + ((b >> 16) & 1u));
    return (a & 0xFFFFu) | (b & 0xFFFF0000u);
}
__device__ __forceinline__ float bf2f(short s) {
    return __uint_as_float(((unsigned)(unsigned short)s) << 16);
}

union U8 { s8v s; unsigned u[4]; };

__global__ __launch_bounds__(256, 6) void hyena_mfma_kernel(
    const float* __restrict__ x1,
    const float* __restrict__ x2,
    const float* __restrict__ v,
    const float* __restrict__ h,
    const float* __restrict__ cb,
    float* __restrict__ out)
{
    __shared__ union SM {
        struct { short zb[TD][ZSTR]; float kl[4][KSTR]; } s1;  // z (bf16) + filters (23.5 KB)
        f4 ob[TD][OB2];                                         // fp32 out staging, half tile (16 KB)
    } sm;

    const int t  = threadIdx.x;
    const int d0 = blockIdx.x * TD;
    const int l0 = blockIdx.y * TL;
    const int b  = blockIdx.z;

    // ---- phase 0: issue ALL z-staging loads into registers (long-latency first) ----
    const int r = t & 15, sbase = t >> 4;
    const size_t rb = ((size_t)(b*DDIM + d0 + r)) * LSEQ;
    f4 xa0[5], xa1[5], xw0[5], xw1[5];
    #pragma unroll
    for (int it = 0; it < 5; ++it) {
        const int gl = l0 - HALO + (sbase + 16*it)*8;
        if (gl >= 0) {
            xa0[it] = *(const f4*)(x2 + rb + gl);
            xa1[it] = *(const f4*)(x2 + rb + gl + 4);
            xw0[it] = *(const f4*)(v  + rb + gl);
            xw1[it] = *(const f4*)(v  + rb + gl + 4);
        }
    }

    // ---- filter build (h loads + expf VALU) overlaps staging-load latency ----
    for (int idx = t; idx < 4*KSTR; idx += 256) {
        const int gl2 = idx / KSTR, mi = idx - gl2*KSTR;
        const int m  = mi - KOFF;
        float val = 0.f;
        if (m >= 0 && m < LC) {
            const int g = (d0 >> 2) + gl2;
            const float dd = __expf((float)g * (2.0f/255.0f) * 2.302585092994046f);
            val = h[g*LC + m] * __expf(-dd * (float)m * (1.0f/127.0f));
        }
        sm.s1.kl[gl2][mi] = val;
    }

    // ---- convert staged regs -> bf16 z in LDS ----
    #pragma unroll
    for (int it = 0; it < 5; ++it) {
        const int s = sbase + 16*it;
        const int gl = l0 - HALO + s*8;
        U8 zz; zz.s = (s8v){0,0,0,0,0,0,0,0};
        if (gl >= 0) {
            const f4 z0 = xa0[it]*xw0[it], z1 = xa1[it]*xw1[it];
            zz.u[0] = bf16pk(z0[0], z0[1]);
            zz.u[1] = bf16pk(z0[2], z0[3]);
            zz.u[2] = bf16pk(z1[0], z1[1]);
            zz.u[3] = bf16pk(z1[2], z1[3]);
        }
        *(s8v*)&sm.s1.zb[r][s*8] = zz.s;
    }

    // ---- lane geometry (MFMA 16x16x32) + early x1 prefetch (before barrier) ----
    const int wv = t >> 6, lane = t & 63;
    const int j  = lane & 15, kb = lane >> 4;
    const int qj = j & 3,  cc = j >> 2;
    const int row = wv*4 + cc;
    const size_t chb = ((size_t)(b*DDIM + d0 + row)) * LSEQ + l0;
    f4 x1r[8];
    #pragma unroll
    for (int ci = 0; ci < 8; ++ci)
        x1r[ci] = *(const f4*)(x1 + chb + 64*ci + 16*qj + 4*kb);
    const float bd = cb[d0 + row];
    __syncthreads();

    // ---- A-frags: A_u[i,p] = k_pad[i - p + 16 + 32u], i = j, p = 8*kb + e ----
    s8v afr[5];
    #pragma unroll
    for (int u = 0; u < 5; ++u) {
        const int M0 = j - 8*kb + 16 + 32*u;
        float kv[8];
        #pragma unroll
        for (int e = 0; e < 8; ++e) kv[e] = sm.s1.kl[wv][M0 - e + KOFF];
        U8 aa;
        aa.u[0] = bf16pk(kv[0], kv[1]);
        aa.u[1] = bf16pk(kv[2], kv[3]);
        aa.u[2] = bf16pk(kv[4], kv[5]);
        aa.u[3] = bf16pk(kv[6], kv[7]);
        afr[u] = aa.s;
    }

    // ---- 8 chains: 5 banded-Toeplitz MFMAs each; bias from LDS bf16 z; gate x1 ----
    f4 ov[8];
    #pragma unroll
    for (int ci = 0; ci < 8; ++ci) {
        const int L = 64*ci + 16*qj;
        f4 acc = {0.f, 0.f, 0.f, 0.f};
        #pragma unroll
        for (int u = 0; u < 5; ++u) {
            int bi = 112 + L + 8*kb - 32*u;      // zb idx of B_u[p=8kb..], incl. halo
            bi = bi < 0 ? 0 : bi;                // clamped reads pair with A == 0
            const s8v bf = *(const s8v*)&sm.s1.zb[row][bi];
            acc = __builtin_amdgcn_mfma_f32_16x16x32_bf16(afr[u], bf, acc, 0, 0, 0);
        }
        const int lo = L + 4*kb;                 // lane's 4 output l's: lo..lo+3
        const s4v z4 = *(const s4v*)&sm.s1.zb[row][HALO + lo];
        f4 o;
        o[0] = (acc[0] + bf2f(z4[0])*bd) * x1r[ci][0];
        o[1] = (acc[1] + bf2f(z4[1])*bd) * x1r[ci][1];
        o[2] = (acc[2] + bf2f(z4[2])*bd) * x1r[ci][2];
        o[3] = (acc[3] + bf2f(z4[3])*bd) * x1r[ci][3];
        ov[ci] = o;
    }

    // ---- output transpose in two 16 KB half-phases (z dead after first barrier) ----
    const int seg = t & 3;
    #pragma unroll
    for (int hp = 0; hp < 2; ++hp) {
        __syncthreads();                         // ob free (zb dead / prev half written)
        #pragma unroll
        for (int ci = 0; ci < 4; ++ci) {
            const int cidx = hp*4 + ci;
            const int J = (4*cidx + qj)*4 + kb - hp*64;   // [0,64)
            sm.ob[row][J ^ (row & 7)] = ov[cidx];
        }
        __syncthreads();
        #pragma unroll
        for (int it = 0; it < 4; ++it) {
            const int ll = (t >> 2) + it*64;     // local l in [0,256)
            const int J = ll >> 2, e = ll & 3;
            f4 o;
            #pragma unroll
            for (int rr = 0; rr < 4; ++rr) {
                const int r2 = seg*4 + rr;
                o[rr] = ((const float*)&sm.ob[r2][J ^ (r2 & 7)])[e];
            }
            *(f4*)(out + ((size_t)b*LSEQ + l0 + hp*256 + ll)*DDIM + d0 + seg*4) = o;
        }
    }
}

extern "C" void kernel_launch(void* const* d_in, const int* in_sizes, int n_in,
                              void* d_out, int out_size, void* d_ws, size_t ws_size,
                              hipStream_t stream) {
    const float* x1 = (const float*)d_in[0];
    const float* x2 = (const float*)d_in[1];
    const float* v  = (const float*)d_in[2];
    const float* h  = (const float*)d_in[3];
    const float* cb = (const float*)d_in[4];
    float* outp = (float*)d_out;
    dim3 grid(DDIM/TD, LSEQ/TL, BB);
    hipLaunchKernelGGL(hyena_mfma_kernel, grid, dim3(256), 0, stream,
                       x1, x2, v, h, cb, outp);
}

// Round 8
// 52.132 us; speedup vs baseline: 1.9534x; 1.7337x over previous
//
#include <hip/hip_runtime.h>

typedef float f4  __attribute__((ext_vector_type(4)));
typedef short s8v __attribute__((ext_vector_type(8)));
typedef short s4v __attribute__((ext_vector_type(4)));

#define BB    2
#define DDIM  1024
#define LSEQ  8192
#define LC    128
#define TD    16      // channels per block = 4 groups, 1 group per wave
#define TL    512     // l-extent per block
#define HALO  128
#define ZSTR  648     // bf16 row stride: 640 data + 8 pad
#define KSTR  176     // padded filter row: index = m + KOFF, m ∈ [-16, 160)
#define KOFF  16
#define OB2   (TL/8)  // 64 f4 per row: half-tile output staging (16 KB)

// round-to-nearest-even fp32 -> bf16, packed pair (lo in bits 0-15)
__device__ __forceinline__ unsigned bf16pk(float lo, float hi) {
    unsigned a = __float_as_uint(lo), b = __float_as_uint(hi);
    a = (a + 0x7FFFu + ((a >> 16) & 1u)) >> 16;
    b = (b + 0x7FFFu + ((b >> 16) & 1u));
    return (a & 0xFFFFu) | (b & 0xFFFF0000u);
}
__device__ __forceinline__ float bf2f(short s) {
    return __uint_as_float(((unsigned)(unsigned short)s) << 16);
}

union U8 { s8v s; unsigned u[4]; };

// NOTE: min-waves arg MUST stay 4 (VGPR cap 128). 5/6 forced VGPR<=102/85 and
// spilled the phase-0 staged tile to scratch (R6: WRITE 215MB, R7: FETCH+52MB).
__global__ __launch_bounds__(256, 4) void hyena_mfma_kernel(
    const float* __restrict__ x1,
    const float* __restrict__ x2,
    const float* __restrict__ v,
    const float* __restrict__ h,
    const float* __restrict__ cb,
    float* __restrict__ out)
{
    __shared__ union SM {
        struct { short zb[TD][ZSTR]; float kl[4][KSTR]; } s1;  // z (bf16) + filters (23.5 KB)
        f4 ob[TD][OB2];                                         // fp32 out staging, half tile (16 KB)
    } sm;

    const int t  = threadIdx.x;
    const int d0 = blockIdx.x * TD;
    const int l0 = blockIdx.y * TL;
    const int b  = blockIdx.z;

    // ---- phase 0: issue ALL z-staging loads into registers (long-latency first) ----
    const int r = t & 15, sbase = t >> 4;
    const size_t rb = ((size_t)(b*DDIM + d0 + r)) * LSEQ;
    f4 xa0[5], xa1[5], xw0[5], xw1[5];
    #pragma unroll
    for (int it = 0; it < 5; ++it) {
        const int gl = l0 - HALO + (sbase + 16*it)*8;
        if (gl >= 0) {
            xa0[it] = *(const f4*)(x2 + rb + gl);
            xa1[it] = *(const f4*)(x2 + rb + gl + 4);
            xw0[it] = *(const f4*)(v  + rb + gl);
            xw1[it] = *(const f4*)(v  + rb + gl + 4);
        }
    }

    // ---- filter build (h loads + expf VALU) overlaps staging-load latency ----
    for (int idx = t; idx < 4*KSTR; idx += 256) {
        const int gl2 = idx / KSTR, mi = idx - gl2*KSTR;
        const int m  = mi - KOFF;
        float val = 0.f;
        if (m >= 0 && m < LC) {
            const int g = (d0 >> 2) + gl2;
            const float dd = __expf((float)g * (2.0f/255.0f) * 2.302585092994046f);
            val = h[g*LC + m] * __expf(-dd * (float)m * (1.0f/127.0f));
        }
        sm.s1.kl[gl2][mi] = val;
    }

    // ---- convert staged regs -> bf16 z in LDS ----
    #pragma unroll
    for (int it = 0; it < 5; ++it) {
        const int s = sbase + 16*it;
        const int gl = l0 - HALO + s*8;
        U8 zz; zz.s = (s8v){0,0,0,0,0,0,0,0};
        if (gl >= 0) {
            const f4 z0 = xa0[it]*xw0[it], z1 = xa1[it]*xw1[it];
            zz.u[0] = bf16pk(z0[0], z0[1]);
            zz.u[1] = bf16pk(z0[2], z0[3]);
            zz.u[2] = bf16pk(z1[0], z1[1]);
            zz.u[3] = bf16pk(z1[2], z1[3]);
        }
        *(s8v*)&sm.s1.zb[r][s*8] = zz.s;
    }

    // ---- lane geometry (MFMA 16x16x32) + early x1 prefetch (before barrier) ----
    const int wv = t >> 6, lane = t & 63;
    const int j  = lane & 15, kb = lane >> 4;
    const int qj = j & 3,  cc = j >> 2;
    const int row = wv*4 + cc;
    const size_t chb = ((size_t)(b*DDIM + d0 + row)) * LSEQ + l0;
    f4 x1r[8];
    #pragma unroll
    for (int ci = 0; ci < 8; ++ci)
        x1r[ci] = *(const f4*)(x1 + chb + 64*ci + 16*qj + 4*kb);
    const float bd = cb[d0 + row];
    __syncthreads();

    // ---- A-frags: A_u[i,p] = k_pad[i - p + 16 + 32u], i = j, p = 8*kb + e ----
    s8v afr[5];
    #pragma unroll
    for (int u = 0; u < 5; ++u) {
        const int M0 = j - 8*kb + 16 + 32*u;
        float kv[8];
        #pragma unroll
        for (int e = 0; e < 8; ++e) kv[e] = sm.s1.kl[wv][M0 - e + KOFF];
        U8 aa;
        aa.u[0] = bf16pk(kv[0], kv[1]);
        aa.u[1] = bf16pk(kv[2], kv[3]);
        aa.u[2] = bf16pk(kv[4], kv[5]);
        aa.u[3] = bf16pk(kv[6], kv[7]);
        afr[u] = aa.s;
    }

    // ---- 8 chains: 5 banded-Toeplitz MFMAs each; bias from LDS bf16 z; gate x1 ----
    f4 ov[8];
    #pragma unroll
    for (int ci = 0; ci < 8; ++ci) {
        const int L = 64*ci + 16*qj;
        f4 acc = {0.f, 0.f, 0.f, 0.f};
        #pragma unroll
        for (int u = 0; u < 5; ++u) {
            int bi = 112 + L + 8*kb - 32*u;      // zb idx of B_u[p=8kb..], incl. halo
            bi = bi < 0 ? 0 : bi;                // clamped reads pair with A == 0
            const s8v bf = *(const s8v*)&sm.s1.zb[row][bi];
            acc = __builtin_amdgcn_mfma_f32_16x16x32_bf16(afr[u], bf, acc, 0, 0, 0);
        }
        const int lo = L + 4*kb;                 // lane's 4 output l's: lo..lo+3
        const s4v z4 = *(const s4v*)&sm.s1.zb[row][HALO + lo];
        f4 o;
        o[0] = (acc[0] + bf2f(z4[0])*bd) * x1r[ci][0];
        o[1] = (acc[1] + bf2f(z4[1])*bd) * x1r[ci][1];
        o[2] = (acc[2] + bf2f(z4[2])*bd) * x1r[ci][2];
        o[3] = (acc[3] + bf2f(z4[3])*bd) * x1r[ci][3];
        ov[ci] = o;
    }

    // ---- output transpose in two 16 KB half-phases (z dead after first barrier) ----
    const int seg = t & 3;
    #pragma unroll
    for (int hp = 0; hp < 2; ++hp) {
        __syncthreads();                         // ob free (zb dead / prev half drained)
        #pragma unroll
        for (int ci = 0; ci < 4; ++ci) {
            const int cidx = hp*4 + ci;
            const int J = (4*cidx + qj)*4 + kb - hp*64;   // [0,64)
            sm.ob[row][J ^ (row & 7)] = ov[cidx];
        }
        __syncthreads();
        #pragma unroll
        for (int it = 0; it < 4; ++it) {
            const int ll = (t >> 2) + it*64;     // local l in [0,256)
            const int J = ll >> 2, e = ll & 3;
            f4 o;
            #pragma unroll
            for (int rr = 0; rr < 4; ++rr) {
                const int r2 = seg*4 + rr;
                o[rr] = ((const float*)&sm.ob[r2][J ^ (r2 & 7)])[e];
            }
            *(f4*)(out + ((size_t)b*LSEQ + l0 + hp*256 + ll)*DDIM + d0 + seg*4) = o;
        }
    }
}

extern "C" void kernel_launch(void* const* d_in, const int* in_sizes, int n_in,
                              void* d_out, int out_size, void* d_ws, size_t ws_size,
                              hipStream_t stream) {
    const float* x1 = (const float*)d_in[0];
    const float* x2 = (const float*)d_in[1];
    const float* v  = (const float*)d_in[2];
    const float* h  = (const float*)d_in[3];
    const float* cb = (const float*)d_in[4];
    float* outp = (float*)d_out;
    dim3 grid(DDIM/TD, LSEQ/TL, BB);
    hipLaunchKernelGGL(hyena_mfma_kernel, grid, dim3(256), 0, stream,
                       x1, x2, v, h, cb, outp);
}

// Round 9
// 51.170 us; speedup vs baseline: 1.9901x; 1.0188x over previous
//
#include <hip/hip_runtime.h>

typedef float f4  __attribute__((ext_vector_type(4)));
typedef short s8v __attribute__((ext_vector_type(8)));
typedef short s4v __attribute__((ext_vector_type(4)));

#define BB    2
#define DDIM  1024
#define LSEQ  8192
#define LC    128
#define TD    16      // channels per block = 4 groups, 1 group per wave
#define TL    512     // l-extent per block
#define HALO  128
#define ZSTR  648     // bf16 row stride: 640 data + 8 pad
#define KSTR  176     // padded filter row: index = m + KOFF, m ∈ [-16, 160)
#define KOFF  16
#define OB2   (TL/8)  // 64 f4 per row: half-tile output staging (16 KB)

// round-to-nearest-even fp32 -> bf16, packed pair (lo in bits 0-15)
__device__ __forceinline__ unsigned bf16pk(float lo, float hi) {
    unsigned a = __float_as_uint(lo), b = __float_as_uint(hi);
    a = (a + 0x7FFFu + ((a >> 16) & 1u)) >> 16;
    b = (b + 0x7FFFu + ((b >> 16) & 1u));
    return (a & 0xFFFFu) | (b & 0xFFFF0000u);
}
__device__ __forceinline__ float bf2f(short s) {
    return __uint_as_float(((unsigned)(unsigned short)s) << 16);
}

union U8 { s8v s; unsigned u[4]; };

// NOTE: min-waves arg MUST stay 4 (VGPR cap 128). 5/6 forced VGPR<=102/85 and
// spilled the phase-0 staged tile to scratch (R6: WRITE 215MB, R7: FETCH+52MB).
__global__ __launch_bounds__(256, 4) void hyena_mfma_kernel(
    const float* __restrict__ x1,
    const float* __restrict__ x2,
    const float* __restrict__ v,
    const float* __restrict__ h,
    const float* __restrict__ cb,
    float* __restrict__ out)
{
    __shared__ union SM {
        struct { short zb[TD][ZSTR]; float kl[4][KSTR]; } s1;  // z (bf16) + filters (23.5 KB)
        f4 ob[TD][OB2];                                         // fp32 out staging, half tile (16 KB)
    } sm;

    const int t = threadIdx.x;

    // ---- XCD-aware decode: all 64 d0-blocks of one (l0,b) share an XCD so the
    //      XCD's L2 assembles full 4KB output lines (round-robin xcd = flat%8) ----
    const int flat = blockIdx.x;
    const int xcd  = flat & 7;
    const int rr_  = flat >> 3;
    const int d0   = (rr_ & 63) * TD;
    const int c_   = xcd + 8*(rr_ >> 6);        // [0,32)
    const int l0   = (c_ & 15) * TL;
    const int b    = c_ >> 4;

    // ---- phase 0: issue ALL z-staging loads into registers (long-latency first) ----
    const int r = t & 15, sbase = t >> 4;
    const size_t rb = ((size_t)(b*DDIM + d0 + r)) * LSEQ;
    f4 xa0[5], xa1[5], xw0[5], xw1[5];
    #pragma unroll
    for (int it = 0; it < 5; ++it) {
        const int gl = l0 - HALO + (sbase + 16*it)*8;
        if (gl >= 0) {
            xa0[it] = *(const f4*)(x2 + rb + gl);
            xa1[it] = *(const f4*)(x2 + rb + gl + 4);
            xw0[it] = *(const f4*)(v  + rb + gl);
            xw1[it] = *(const f4*)(v  + rb + gl + 4);
        }
    }

    // ---- filter build (h loads + expf VALU) overlaps staging-load latency ----
    for (int idx = t; idx < 4*KSTR; idx += 256) {
        const int gl2 = idx / KSTR, mi = idx - gl2*KSTR;
        const int m  = mi - KOFF;
        float val = 0.f;
        if (m >= 0 && m < LC) {
            const int g = (d0 >> 2) + gl2;
            const float dd = __expf((float)g * (2.0f/255.0f) * 2.302585092994046f);
            val = h[g*LC + m] * __expf(-dd * (float)m * (1.0f/127.0f));
        }
        sm.s1.kl[gl2][mi] = val;
    }

    // ---- convert staged regs -> bf16 z in LDS ----
    #pragma unroll
    for (int it = 0; it < 5; ++it) {
        const int s = sbase + 16*it;
        const int gl = l0 - HALO + s*8;
        U8 zz; zz.s = (s8v){0,0,0,0,0,0,0,0};
        if (gl >= 0) {
            const f4 z0 = xa0[it]*xw0[it], z1 = xa1[it]*xw1[it];
            zz.u[0] = bf16pk(z0[0], z0[1]);
            zz.u[1] = bf16pk(z0[2], z0[3]);
            zz.u[2] = bf16pk(z1[0], z1[1]);
            zz.u[3] = bf16pk(z1[2], z1[3]);
        }
        *(s8v*)&sm.s1.zb[r][s*8] = zz.s;
    }

    // ---- lane geometry (MFMA 16x16x32) + early x1 prefetch (before barrier) ----
    const int wv = t >> 6, lane = t & 63;
    const int j  = lane & 15, kb = lane >> 4;
    const int qj = j & 3,  cc = j >> 2;
    const int row = wv*4 + cc;
    const size_t chb = ((size_t)(b*DDIM + d0 + row)) * LSEQ + l0;
    f4 x1r[8];
    #pragma unroll
    for (int ci = 0; ci < 8; ++ci)
        x1r[ci] = *(const f4*)(x1 + chb + 64*ci + 16*qj + 4*kb);
    const float bd = cb[d0 + row];
    __syncthreads();

    // ---- A-frags: A_u[i,p] = k_pad[i - p + 16 + 32u], i = j, p = 8*kb + e ----
    s8v afr[5];
    #pragma unroll
    for (int u = 0; u < 5; ++u) {
        const int M0 = j - 8*kb + 16 + 32*u;
        float kv[8];
        #pragma unroll
        for (int e = 0; e < 8; ++e) kv[e] = sm.s1.kl[wv][M0 - e + KOFF];
        U8 aa;
        aa.u[0] = bf16pk(kv[0], kv[1]);
        aa.u[1] = bf16pk(kv[2], kv[3]);
        aa.u[2] = bf16pk(kv[4], kv[5]);
        aa.u[3] = bf16pk(kv[6], kv[7]);
        afr[u] = aa.s;
    }

    // ---- 8 chains: 5 banded-Toeplitz MFMAs each; bias from LDS bf16 z; gate x1 ----
    f4 ov[8];
    #pragma unroll
    for (int ci = 0; ci < 8; ++ci) {
        const int L = 64*ci + 16*qj;
        f4 acc = {0.f, 0.f, 0.f, 0.f};
        #pragma unroll
        for (int u = 0; u < 5; ++u) {
            int bi = 112 + L + 8*kb - 32*u;      // zb idx of B_u[p=8kb..], incl. halo
            bi = bi < 0 ? 0 : bi;                // clamped reads pair with A == 0
            const s8v bf = *(const s8v*)&sm.s1.zb[row][bi];
            acc = __builtin_amdgcn_mfma_f32_16x16x32_bf16(afr[u], bf, acc, 0, 0, 0);
        }
        const int lo = L + 4*kb;                 // lane's 4 output l's: lo..lo+3
        const s4v z4 = *(const s4v*)&sm.s1.zb[row][HALO + lo];
        f4 o;
        o[0] = (acc[0] + bf2f(z4[0])*bd) * x1r[ci][0];
        o[1] = (acc[1] + bf2f(z4[1])*bd) * x1r[ci][1];
        o[2] = (acc[2] + bf2f(z4[2])*bd) * x1r[ci][2];
        o[3] = (acc[3] + bf2f(z4[3])*bd) * x1r[ci][3];
        ov[ci] = o;
    }

    // ---- output transpose in two 16 KB half-phases (z dead after first barrier) ----
    const int seg = t & 3;
    #pragma unroll
    for (int hp = 0; hp < 2; ++hp) {
        __syncthreads();                         // ob free (zb dead / prev half drained)
        #pragma unroll
        for (int ci = 0; ci < 4; ++ci) {
            const int cidx = hp*4 + ci;
            const int J = (4*cidx + qj)*4 + kb - hp*64;   // [0,64)
            sm.ob[row][J ^ (row & 7)] = ov[cidx];
        }
        __syncthreads();
        #pragma unroll
        for (int it = 0; it < 4; ++it) {
            const int ll = (t >> 2) + it*64;     // local l in [0,256)
            const int J = ll >> 2, e = ll & 3;
            f4 o;
            #pragma unroll
            for (int rr2 = 0; rr2 < 4; ++rr2) {
                const int r2 = seg*4 + rr2;
                o[rr2] = ((const float*)&sm.ob[r2][J ^ (r2 & 7)])[e];
            }
            *(f4*)(out + ((size_t)b*LSEQ + l0 + hp*256 + ll)*DDIM + d0 + seg*4) = o;
        }
    }
}

extern "C" void kernel_launch(void* const* d_in, const int* in_sizes, int n_in,
                              void* d_out, int out_size, void* d_ws, size_t ws_size,
                              hipStream_t stream) {
    const float* x1 = (const float*)d_in[0];
    const float* x2 = (const float*)d_in[1];
    const float* v  = (const float*)d_in[2];
    const float* h  = (const float*)d_in[3];
    const float* cb = (const float*)d_in[4];
    float* outp = (float*)d_out;
    hipLaunchKernelGGL(hyena_mfma_kernel, dim3(2048), dim3(256), 0, stream,
                       x1, x2, v, h, cb, outp);
}